// Round 3
// baseline (536.418 us; speedup 1.0000x reference)
//
#include <hip/hip_runtime.h>

#define H  400
#define NB 16
#define CI 4
#define CO 32

// ---------------- K1: transpose each 400x400 plane of X into XT ----------------
#define TT 80
__global__ __launch_bounds__(256) void k_transpose(const float* __restrict__ x,
                                                   float* __restrict__ xt) {
    __shared__ float tile[TT][TT + 5];
    int b = blockIdx.x;
    int tj = b % 5;
    int ti = (b / 5) % 5;
    int nc = b / 25;
    const float* src = x + (size_t)nc * H * H;
    float* dst = xt + (size_t)nc * H * H;
    int i0 = ti * TT, j0 = tj * TT;
    for (int e = threadIdx.x; e < TT * 20; e += 256) {
        int r = e / 20, q = e % 20;
        float4 v = ((const float4*)(src + (size_t)(i0 + r) * H + j0))[q];
        tile[r][q * 4 + 0] = v.x; tile[r][q * 4 + 1] = v.y;
        tile[r][q * 4 + 2] = v.z; tile[r][q * 4 + 3] = v.w;
    }
    __syncthreads();
    for (int e = threadIdx.x; e < TT * 20; e += 256) {
        int r = e / 20, q = e % 20;
        float4 v;
        v.x = tile[q * 4 + 0][r]; v.y = tile[q * 4 + 1][r];
        v.z = tile[q * 4 + 2][r]; v.w = tile[q * 4 + 3][r];
        ((float4*)(dst + (size_t)(j0 + r) * H + i0))[q] = v;
    }
}

// ---------------- K2: partial rows/cols, k-split x5 ----------------
#define KC 40
#define KSPLIT 5
__global__ __launch_bounds__(256) void k_rowscols(const float* __restrict__ x,
        const float* __restrict__ xt, const float* __restrict__ L,
        float* __restrict__ rowsP, float* __restrict__ colsP)
{
    __shared__ __align__(16) float4 Lm[CO * CI];
    __shared__ __align__(16) float Xr[NB * CI * KC];
    __shared__ __align__(16) float Xc[NB * CI * KC];
    __shared__ __align__(16) float Tr[CO * 164];
    int b = blockIdx.x;
    int m  = b / KSPLIT;
    int ks = b % KSPLIT;
    int tid = threadIdx.x;
    const float4* L4 = (const float4*)L;
    if (tid < CO * CI) Lm[tid] = L4[tid * H + m];

    int o  = tid & 31;
    int n0 = tid >> 5;
    int n1 = n0 + 8;
    float ar0 = 0.f, ar1 = 0.f, ac0 = 0.f, ac1 = 0.f;

    for (int ch = 0; ch < 2; ++ch) {
        int k0 = ks * 80 + ch * KC;
        __syncthreads();
        for (int e = tid; e < NB * CI * KC / 4; e += 256) {
            int q  = e % 10;
            int nc = e / 10;
            ((float4*)Xr)[e] = *(const float4*)(x  + (size_t)(nc * H + m) * H + k0 + q * 4);
            ((float4*)Xc)[e] = *(const float4*)(xt + (size_t)(nc * H + m) * H + k0 + q * 4);
        }
        for (int e = tid; e < CO * CI * KC; e += 256) {
            int k  = e % KC;
            int oc = e / KC;
            float4 lv = L4[oc * H + k0 + k];
            float4 lm = Lm[oc];
            Tr[(oc >> 2) * 164 + (oc & 3) * KC + k] =
                lv.x * lm.x + lv.y * lm.y + lv.z * lm.z + lv.w * lm.w;
        }
        __syncthreads();
        #pragma unroll
        for (int c = 0; c < CI; ++c) {
            const float4* trp = (const float4*)(Tr + o * 164 + c * KC);
            const float4* pr0 = (const float4*)(Xr + (n0 * CI + c) * KC);
            const float4* pr1 = (const float4*)(Xr + (n1 * CI + c) * KC);
            const float4* pc0 = (const float4*)(Xc + (n0 * CI + c) * KC);
            const float4* pc1 = (const float4*)(Xc + (n1 * CI + c) * KC);
            #pragma unroll
            for (int q = 0; q < KC / 4; ++q) {
                float4 tv = trp[q];
                float4 a  = pr0[q];
                float4 bb = pr1[q];
                float4 cc = pc0[q];
                float4 dd = pc1[q];
                ar0 += tv.x * a.x  + tv.y * a.y  + tv.z * a.z  + tv.w * a.w;
                ar1 += tv.x * bb.x + tv.y * bb.y + tv.z * bb.z + tv.w * bb.w;
                ac0 += tv.x * cc.x + tv.y * cc.y + tv.z * cc.z + tv.w * cc.w;
                ac1 += tv.x * dd.x + tv.y * dd.y + tv.z * dd.z + tv.w * dd.w;
            }
        }
    }
    size_t base = (size_t)ks * NB * CO * H;
    rowsP[base + (size_t)(n0 * CO + o) * H + m] = ar0;
    rowsP[base + (size_t)(n1 * CO + o) * H + m] = ar1;
    colsP[base + (size_t)(n0 * CO + o) * H + m] = ac0;
    colsP[base + (size_t)(n1 * CO + o) * H + m] = ac1;
}

// ---------------- K2b: reduce the 5 partials ----------------
__global__ __launch_bounds__(256) void k_reduce(const float* __restrict__ rowsP,
        const float* __restrict__ colsP, float* __restrict__ rows, float* __restrict__ cols)
{
    int i = blockIdx.x * 256 + threadIdx.x;
    if (i < NB * CO * H) {
        float s = 0.f, t = 0.f;
        #pragma unroll
        for (int k = 0; k < KSPLIT; ++k) {
            s += rowsP[(size_t)k * NB * CO * H + i];
            t += colsP[(size_t)k * NB * CO * H + i];
        }
        rows[i] = s;
        cols[i] = t;
    }
}

// ---------------- K3: final output, 8x32 tiles (128-B aligned full-line stores) ----
// grid = 4 nq * 50 ib * 13 jb = 2600 blocks, 512 threads.
// jb=12 is an overlapping band at j0=368 (j 368..383 double-written, identical values).
// Per (n,o): 8x32 tile = 64 float4s = exactly one wave; stores are 8 full cachelines.
#define OI 8
#define OJ 32
__global__ __launch_bounds__(512) void k_out(const float* __restrict__ x,
        const float* __restrict__ L, const float* __restrict__ bias,
        const float* __restrict__ rows, const float* __restrict__ cols,
        float* __restrict__ out)
{
    __shared__ __align__(16) float Xl[16 * OI * OJ];   // 16 KB  [pl=nl*4+c][i][j]
    __shared__ __align__(16) float rT[4 * 8 * OI];     // 1 KB   [nl][o][i]
    __shared__ __align__(16) float cT[4 * 8 * OJ];     // 4 KB   [nl][o][j]
    int b  = blockIdx.x;
    int nq = b / 650;
    int r2 = b % 650;
    int ib = r2 / 13, jb = r2 % 13;
    int i0 = ib * OI;
    int j0 = (jb < 12) ? jb * OJ : (H - OJ);
    int n0 = nq * 4;            // this block handles n = n0..n0+3
    int tid = threadIdx.x;

    const float4* x4 = (const float4*)x;
    float4* Xl4 = (float4*)Xl;
    // stage X: 16 planes x 8 rows x 8 quads = 1024 float4 (each row = 1 full line)
    for (int e = tid; e < 1024; e += 512) {
        int q  = e & 7;
        int i  = (e >> 3) & 7;
        int pl = e >> 6;
        Xl4[e] = x4[(size_t)(n0 * 4 + pl) * (H * 100) + (size_t)(i0 + i) * 100 + (j0 >> 2) + q];
    }

    int o    = tid >> 6;        // 0..7
    int lane = tid & 63;
    int i    = lane >> 3;       // 0..7
    int jq   = lane & 7;        // quad within row
    int gi   = i0 + i;
    int gj4  = (j0 >> 2) + jq;
    const float4* L4  = (const float4*)L;
    const float4* cT4 = (const float4*)cT;
    float4* out4 = (float4*)out;

    for (int os = 0; os < 4; ++os) {
        int og = os * 8 + o;
        float4 T4[CI];
        #pragma unroll
        for (int c = 0; c < CI; ++c) {
            float4 Li = L4[(og * CI + c) * H + gi];
            float4 La = L4[(og * CI + c) * H + j0 + jq * 4 + 0];
            float4 Lb = L4[(og * CI + c) * H + j0 + jq * 4 + 1];
            float4 Lc = L4[(og * CI + c) * H + j0 + jq * 4 + 2];
            float4 Ld = L4[(og * CI + c) * H + j0 + jq * 4 + 3];
            T4[c].x = Li.x * La.x + Li.y * La.y + Li.z * La.z + Li.w * La.w;
            T4[c].y = Li.x * Lb.x + Li.y * Lb.y + Li.z * Lb.z + Li.w * Lb.w;
            T4[c].z = Li.x * Lc.x + Li.y * Lc.y + Li.z * Lc.z + Li.w * Lc.w;
            T4[c].w = Li.x * Ld.x + Li.y * Ld.y + Li.z * Ld.z + Li.w * Ld.w;
        }
        float bo = bias[og];

        __syncthreads();   // prev-os readers done (os=0: X staging done)
        if (tid < 256) {   // rT: [nl][oo][ii] = 256 floats
            int ii = tid & 7, oo = (tid >> 3) & 7, nl = tid >> 6;
            rT[tid] = rows[(size_t)((n0 + nl) * CO + os * 8 + oo) * H + i0 + ii];
        }
        for (int e = tid; e < 1024; e += 512) {  // cT: [nl][oo][jj]
            int jj = e & 31, oo = (e >> 5) & 7, nl = e >> 8;
            cT[e] = cols[(size_t)((n0 + nl) * CO + os * 8 + oo) * H + j0 + jj];
        }
        __syncthreads();

        #pragma unroll
        for (int nl = 0; nl < 4; ++nl) {
            float ra = rT[(nl * 8 + o) * OI + i] + bo;
            float4 ca = cT4[(nl * 8 + o) * (OJ / 4) + jq];
            float4 acc;
            acc.x = ra + ca.x; acc.y = ra + ca.y; acc.z = ra + ca.z; acc.w = ra + ca.w;
            #pragma unroll
            for (int c = 0; c < CI; ++c) {
                float4 xv = Xl4[((nl * 4 + c) * OI + i) * (OJ / 4) + jq];
                acc.x -= xv.x * T4[c].x;
                acc.y -= xv.y * T4[c].y;
                acc.z -= xv.z * T4[c].z;
                acc.w -= xv.w * T4[c].w;
            }
            out4[(size_t)((n0 + nl) * CO + og) * (H * 100) + (size_t)gi * 100 + gj4] = acc;
        }
    }
}

extern "C" void kernel_launch(void* const* d_in, const int* in_sizes, int n_in,
                              void* d_out, int out_size, void* d_ws, size_t ws_size,
                              hipStream_t stream) {
    const float* x    = (const float*)d_in[0];
    const float* L    = (const float*)d_in[1];
    const float* bias = (const float*)d_in[2];
    float* out = (float*)d_out;
    char* ws = (char*)d_ws;

    size_t xt_bytes = (size_t)NB * CI * H * H * sizeof(float);
    size_t rc_elems = (size_t)NB * CO * H;
    size_t rcP_bytes = (size_t)KSPLIT * rc_elems * sizeof(float);
    size_t rc_bytes  = rc_elems * sizeof(float);

    float* XT    = (float*)ws;
    float* rowsP = (float*)(ws + xt_bytes);
    float* colsP = (float*)(ws + xt_bytes + rcP_bytes);
    float* rows  = (float*)(ws + xt_bytes + 2 * rcP_bytes);
    float* cols  = (float*)(ws + xt_bytes + 2 * rcP_bytes + rc_bytes);
    (void)ws_size;

    k_transpose<<<1600, 256, 0, stream>>>(x, XT);
    k_rowscols<<<H * KSPLIT, 256, 0, stream>>>(x, XT, L, rowsP, colsP);
    k_reduce<<<(NB * CO * H + 255) / 256, 256, 0, stream>>>(rowsP, colsP, rows, cols);
    k_out<<<2600, 512, 0, stream>>>(x, L, bias, rows, cols, out);
}